// Round 3
// baseline (1377.652 us; speedup 1.0000x reference)
//
#include <hip/hip_runtime.h>
#include <math.h>

#define N_NODES 16384
#define N_EDGES 524288
#define D_FEAT  128
#define BATCH   4
#define NPTS    4096   // points per cloud
#define KSEL    2048   // selected per cloud
#define MSEL    (BATCH*KSEL)  // 8192

#define X16(F) F(0) F(1) F(2) F(3) F(4) F(5) F(6) F(7) \
               F(8) F(9) F(10) F(11) F(12) F(13) F(14) F(15)

// ---------------------------------------------------------------------------
// FPS: 256 threads x 16 points (the measured-1102us structure). R2 taught us:
// 512thr/2 waves-per-SIMD REGRESSED (+127us) — per-wave overhead (DPP chain,
// packing, tree, barrier) duplicates per SIMD and barrier-lockstep kills the
// hoped-for overlap. Occupancy does NOT help a per-iteration-barrier kernel.
// This round's single change: cross-wave reduce via ds_max_u64 atomic on one
// LDS slot (3-slot rotation for race-free reset) instead of 4-slot write +
// 4x ds_read_b64 + 64-bit compare tree. Removes ~40-60cy of post-barrier
// serial work per iteration.
// Regression log (do not reintroduce without counter evidence):
//   512thr/8wave +127us (R2); pk-asm packed math +100us; tournament-tree
//   argmax +20-60us; two-phase f32/u32 reduce +160us; float4-interleaved
//   query +worse; fusing deg blocks into this dispatch +60us AND races.
// inv is initialized by hipMemsetAsync(0xFF) BEFORE this kernel launches.
// ---------------------------------------------------------------------------

__device__ __forceinline__ unsigned long long dpp_max_step(unsigned long long p,
                                                           unsigned int slo,
                                                           unsigned int shi)
{
    unsigned long long s = (((unsigned long long)shi) << 32) | slo;
    return (s > p) ? s : p;
}

__launch_bounds__(256, 1)
__global__ void fps_kernel(const float* __restrict__ pos,
                           int* __restrict__ fp_int,
                           int* __restrict__ inv,
                           float* __restrict__ out_subx,
                           float* __restrict__ out_fp)
{
    __shared__ float sx[NPTS];
    __shared__ float sy[NPTS];
    __shared__ float sz[NPTS];
    __shared__ int   sel[KSEL];
    __shared__ unsigned long long wmax[3];   // 3-slot rotation, see proof below

    const int b   = blockIdx.x;
    const int tid = threadIdx.x;

    const float* gp = pos + (size_t)b * NPTS * 3;
    for (int i = tid; i < NPTS; i += 256) {
        sx[i] = gp[3 * i + 0];
        sy[i] = gp[3 * i + 1];
        sz[i] = gp[3 * i + 2];
    }
    if (tid < 3) wmax[tid] = 0ULL;   // identity for max (packed keys are > 0)
    __syncthreads();

#define DECL(J) float x##J, y##J, z##J, d##J;
    X16(DECL)
#undef DECL
#define LOAD(J) { int li = (J)*256 + tid; x##J = sx[li]; y##J = sy[li]; z##J = sz[li]; d##J = 1e10f; }
    X16(LOAD)
#undef LOAD

    int cur = 0;
    for (int t = 0; t < KSEL; ++t) {
        if (tid == 0) sel[t] = cur;
        float qx = sx[cur];
        float qy = sy[cur];
        float qz = sz[cur];

        float bv = -1.0f;
        int   bi = 0x7fffffff;
        // exact reference arithmetic: (dx*dx + dy*dy) + dz*dz, no fma; fminf;
        // strict > keeps smallest index on ties (j ascending = idx ascending)
#define UPD(J) { \
        float dx = __fsub_rn(x##J, qx); \
        float dy = __fsub_rn(y##J, qy); \
        float dz = __fsub_rn(z##J, qz); \
        float dd = __fadd_rn(__fadd_rn(__fmul_rn(dx, dx), __fmul_rn(dy, dy)), \
                             __fmul_rn(dz, dz)); \
        d##J = fminf(d##J, dd); \
        if (d##J > bv) { bv = d##J; bi = (J)*256 + tid; } }
        X16(UPD)
#undef UPD

        // pack: nonneg float bits are order-preserving as unsigned;
        // tie -> larger ~idx -> smaller idx (matches argmax first-occurrence)
        unsigned long long p =
            (((unsigned long long)__float_as_uint(bv)) << 32) |
            (unsigned int)(~bi);

        // DPP wave-64 max reduce into lane 63
        {
            unsigned int lo, hi, slo, shi;
#define DSTEP(CTRL) \
            lo = (unsigned int)p; hi = (unsigned int)(p >> 32); \
            slo = __builtin_amdgcn_update_dpp(0, (int)lo, CTRL, 0xf, 0xf, true); \
            shi = __builtin_amdgcn_update_dpp(0, (int)hi, CTRL, 0xf, 0xf, true); \
            p = dpp_max_step(p, slo, shi);
            DSTEP(0x111)  // row_shr:1
            DSTEP(0x112)  // row_shr:2
            DSTEP(0x114)  // row_shr:4
            DSTEP(0x118)  // row_shr:8
            DSTEP(0x142)  // row_bcast:15
            DSTEP(0x143)  // row_bcast:31
#undef DSTEP
        }

        // cross-wave combine: one ds_max_u64 per wave into slot t%3.
        // Slot lifecycle proof: slot q=t%3 is max'd in (barrier(t-1),barrier(t)),
        // read in (barrier(t),barrier(t+1)). Thread 0 zeroes slot (t+2)%3 —
        // last read in (barrier(t-1),barrier(t)) [iter t-1], next max'd in
        // (barrier(t+1),barrier(t+2)) [iter t+2] — the zero sits in
        // (barrier(t),barrier(t+1)), barrier-separated from both. Race-free.
        int q = t % 3;
        if ((tid & 63) == 63) atomicMax(&wmax[q], p);
        __syncthreads();

        unsigned long long mm = wmax[q];
        if (tid == 0) wmax[(t + 2) % 3] = 0ULL;
        cur = (int)(~(unsigned int)(mm & 0xffffffffULL));
    }
    __syncthreads();

    // epilogue: write selections in parallel, coalesced
    for (int t = tid; t < KSEL; t += 256) {
        int c = sel[t];
        int g = b * NPTS + c;
        int m = b * KSEL + t;
        fp_int[m] = g;
        inv[g] = m;
        out_fp[m] = (float)g;
        out_subx[m * 3 + 0] = sx[c];
        out_subx[m * 3 + 1] = sy[c];
        out_subx[m * 3 + 2] = sz[c];
    }
}

// ---------------- in-degree histogram --------------------------------------
// inv init moved to hipMemsetAsync(0xFF): deg is now pure edge atomics.
__global__ void deg_kernel(const int* __restrict__ dst, int* __restrict__ deg)
{
    int e = blockIdx.x * blockDim.x + threadIdx.x;
    if (e < N_EDGES) atomicAdd(&deg[dst[e]], 1);
}

// ---------------- exclusive scan over deg -> row_ptr (+ cursor copy) ------
__global__ void scan_kernel(const int* __restrict__ deg, int* __restrict__ row_ptr,
                            int* __restrict__ row_ptr2)
{
    __shared__ int part[1024];
    int tid = threadIdx.x;
    int base = tid * 16;
    int local[16];
    int s = 0;
#pragma unroll
    for (int j = 0; j < 16; ++j) { local[j] = s; s += deg[base + j]; }
    part[tid] = s;
    __syncthreads();
    for (int off = 1; off < 1024; off <<= 1) {
        int v = part[tid];
        int add = (tid >= off) ? part[tid - off] : 0;
        __syncthreads();
        part[tid] = v + add;
        __syncthreads();
    }
    int prefix = (tid == 0) ? 0 : part[tid - 1];
#pragma unroll
    for (int j = 0; j < 16; ++j) {
        int v = prefix + local[j];
        row_ptr[base + j]  = v;
        row_ptr2[base + j] = v;   // consumed (destroyed) by scatter as cursor
    }
    if (tid == 1023) row_ptr[N_NODES] = part[1023];
}

// ---------------- filtered CSR scatter (post-fps) --------------------------
// Runs AFTER fps: inv identifies sampled nodes, so we only place edges whose
// dst is sampled (~50% of edges -> half the atomics and col writes). Sampled
// rows are still densely filled [row_ptr[v], row_ptr[v]+deg[v]) because ALL
// in-edges of a sampled node pass the filter; unsampled rows are never read.
__global__ void scatter_kernel(const int* __restrict__ src, const int* __restrict__ dst,
                               const int* __restrict__ inv,
                               int* __restrict__ row_ptr2, int* __restrict__ col)
{
    int e = blockIdx.x * blockDim.x + threadIdx.x;
    if (e < N_EDGES) {
        int d_ = dst[e];
        if (inv[d_] >= 0) {
            int r = atomicAdd(&row_ptr2[d_], 1);  // returns absolute slot
            col[r] = src[e];
        }
    }
}

// ---------------- fused agg (blocks 0..2047) + edge (blocks 2048..4095) ---
__global__ void agg_edge_kernel(const float* __restrict__ feat,
                                const int* __restrict__ fp_int,
                                const int* __restrict__ row_ptr,
                                const int* __restrict__ col,
                                const int* __restrict__ deg,
                                float* __restrict__ out_subfeat,
                                const int* __restrict__ src,
                                const int* __restrict__ dst,
                                const int* __restrict__ inv,
                                const float* __restrict__ subx,
                                float* __restrict__ outd,
                                float* __restrict__ outw,
                                float* __restrict__ outm)
{
    if (blockIdx.x < 2048) {
        // mean aggregation: one wave per sampled node.
        // Dual-edge scheme: lanes 0-31 accumulate the even-edge stream (A),
        // lanes 32-63 the odd-edge stream (B); each lane loads a float4
        // (16 B — dwordx4 sweet spot). Per-column association is
        // bit-identical to the a/b two-stream unroll: Σ(even e) + Σ(odd e).
        int wid  = (blockIdx.x * blockDim.x + threadIdx.x) >> 6;
        int lane = threadIdx.x & 63;
        int half = lane >> 5;      // 0 = even-edge stream, 1 = odd-edge stream
        int l32  = lane & 31;      // column group: cols 4*l32 .. 4*l32+3
        int v  = fp_int[wid];
        int s0 = row_ptr[v];
        int s1 = row_ptr[v + 1];
        float ax = 0.0f, ay = 0.0f, az = 0.0f, aw = 0.0f;
        int e = s0;
        for (; e + 1 < s1; e += 2) {
            int sE = col[e + half];
            float4 f = ((const float4*)(feat + (size_t)sE * D_FEAT))[l32];
            ax += f.x; ay += f.y; az += f.z; aw += f.w;
        }
        if (e < s1 && half == 0) {   // odd tail goes to the even stream (as before)
            int sE = col[e];
            float4 f = ((const float4*)(feat + (size_t)sE * D_FEAT))[l32];
            ax += f.x; ay += f.y; az += f.z; aw += f.w;
        }
        // combine streams: lane l<32 holds A(cols 4l..), lane l+32 holds B(same cols)
        ax += __shfl_xor(ax, 32, 64);
        ay += __shfl_xor(ay, 32, 64);
        az += __shfl_xor(az, 32, 64);
        aw += __shfl_xor(aw, 32, 64);
        if (half == 0) {
            float dv = fmaxf((float)deg[v], 1.0f);
            float4 o;
            o.x = ax / dv; o.y = ay / dv; o.z = az / dv; o.w = aw / dv;
            ((float4*)(out_subfeat + (size_t)wid * D_FEAT))[l32] = o;
        }
    } else {
        int e = (blockIdx.x - 2048) * blockDim.x + threadIdx.x;
        int ls = inv[src[e]];
        int ld = inv[dst[e]];
        bool mk = (ls >= 0) && (ld >= 0);
        float dx = 0.0f, dy = 0.0f, dz = 0.0f;
        if (mk) {
            dx = __fsub_rn(subx[ld * 3 + 0], subx[ls * 3 + 0]);
            dy = __fsub_rn(subx[ld * 3 + 1], subx[ls * 3 + 1]);
            dz = __fsub_rn(subx[ld * 3 + 2], subx[ls * 3 + 2]);
        }
        float w = sqrtf(__fadd_rn(__fadd_rn(__fmul_rn(dx, dx), __fmul_rn(dy, dy)),
                                  __fmul_rn(dz, dz)));
        outd[e * 3 + 0] = dx;
        outd[e * 3 + 1] = dy;
        outd[e * 3 + 2] = dz;
        outw[e] = w;
        outm[e] = mk ? 1.0f : 0.0f;
    }
}

// ---------------- launch ---------------------------------------------------
// Order: memset(deg)=0, memset(inv)=0xFF (-1), deg, scan, fps, scatter, agg.
// scatter needs inv (fps) + row_ptr2 (scan); agg needs col (scatter).
extern "C" void kernel_launch(void* const* d_in, const int* in_sizes, int n_in,
                              void* d_out, int out_size, void* d_ws, size_t ws_size,
                              hipStream_t stream)
{
    const float* pos  = (const float*)d_in[0];   // [16384,3]
    const float* feat = (const float*)d_in[1];   // [16384,128]
    const int*   src  = (const int*)d_in[2];     // [524288]
    const int*   dst  = (const int*)d_in[3];     // [524288]

    float* out = (float*)d_out;
    float* out_subx    = out;                                 // [8192,3]
    float* out_subfeat = out_subx + (size_t)MSEL * 3;         // [8192,128]
    float* out_d       = out_subfeat + (size_t)MSEL * D_FEAT; // [524288,3]
    float* out_w       = out_d + (size_t)N_EDGES * 3;         // [524288]
    float* out_m       = out_w + (size_t)N_EDGES;             // [524288]
    float* out_fp      = out_m + (size_t)N_EDGES;             // [8192]

    int* fp_int   = (int*)d_ws;               // 8192
    int* inv      = fp_int + MSEL;            // 16384
    int* deg      = inv + N_NODES;            // 16384
    int* row_ptr  = deg + N_NODES;            // 16385
    int* row_ptr2 = row_ptr + (N_NODES + 1);  // 16385
    int* col      = row_ptr2 + (N_NODES + 1); // 524288

    (void)hipMemsetAsync(deg, 0, (size_t)N_NODES * 4, stream);
    (void)hipMemsetAsync(inv, 0xFF, (size_t)N_NODES * 4, stream);  // inv = -1

    deg_kernel<<<N_EDGES / 256, 256, 0, stream>>>(dst, deg);
    scan_kernel<<<1, 1024, 0, stream>>>(deg, row_ptr, row_ptr2);

    fps_kernel<<<BATCH, 256, 0, stream>>>(pos, fp_int, inv, out_subx, out_fp);

    scatter_kernel<<<N_EDGES / 256, 256, 0, stream>>>(src, dst, inv, row_ptr2, col);

    agg_edge_kernel<<<4096, 256, 0, stream>>>(feat, fp_int, row_ptr, col, deg,
                                              out_subfeat, src, dst, inv, out_subx,
                                              out_d, out_w, out_m);
}

// Round 4
// 1215.631 us; speedup vs baseline: 1.1333x; 1.1333x over previous
//
#include <hip/hip_runtime.h>
#include <math.h>

#define N_NODES 16384
#define N_EDGES 524288
#define D_FEAT  128
#define BATCH   4
#define NPTS    4096   // points per cloud
#define KSEL    2048   // selected per cloud
#define MSEL    (BATCH*KSEL)  // 8192
#define CAP     80     // per-sampled-node bucket capacity; deg~Poisson(32),
                       // P(deg>=80) ~ 4e-13/node -> safe; clamped anyway

#define X16(F) F(0) F(1) F(2) F(3) F(4) F(5) F(6) F(7) \
               F(8) F(9) F(10) F(11) F(12) F(13) F(14) F(15)

// ---------------------------------------------------------------------------
// FPS: byte-identical to the measured-1102.6us R1 variant. Do not touch.
// Regression log (do not reintroduce without counter evidence):
//   512thr/2-waves-per-SIMD +127us (R2: barrier-lockstep kills wave overlap;
//     per-wave overhead duplicates);
//   LDS atomicMax(u64) reduce +150us (R3: CAS-loop/RMW on the pre-barrier
//     lgkmcnt path, 4-wave contention serializes — fire-and-forget ds_write +
//     redundant per-thread tree is optimal);
//   pk-asm packed math +100us; tournament-tree argmax +20-60us; two-phase
//   f32/u32 reduce +160us; float4-interleaved query +worse; fusing deg
//   blocks into this dispatch +60us AND races on inv.
// inv is initialized by hipMemsetAsync(0xFF) BEFORE this kernel launches.
// ---------------------------------------------------------------------------

__device__ __forceinline__ unsigned long long dpp_max_step(unsigned long long p,
                                                           unsigned int slo,
                                                           unsigned int shi)
{
    unsigned long long s = (((unsigned long long)shi) << 32) | slo;
    return (s > p) ? s : p;
}

__launch_bounds__(256, 1)
__global__ void fps_kernel(const float* __restrict__ pos,
                           int* __restrict__ fp_int,
                           int* __restrict__ inv,
                           float* __restrict__ out_subx,
                           float* __restrict__ out_fp)
{
    __shared__ float sx[NPTS];
    __shared__ float sy[NPTS];
    __shared__ float sz[NPTS];
    __shared__ int   sel[KSEL];
    __shared__ unsigned long long pwv[2][4];

    const int b   = blockIdx.x;
    const int tid = threadIdx.x;

    const float* gp = pos + (size_t)b * NPTS * 3;
    for (int i = tid; i < NPTS; i += 256) {
        sx[i] = gp[3 * i + 0];
        sy[i] = gp[3 * i + 1];
        sz[i] = gp[3 * i + 2];
    }
    __syncthreads();

#define DECL(J) float x##J, y##J, z##J, d##J;
    X16(DECL)
#undef DECL
#define LOAD(J) { int li = (J)*256 + tid; x##J = sx[li]; y##J = sy[li]; z##J = sz[li]; d##J = 1e10f; }
    X16(LOAD)
#undef LOAD

    int cur = 0;
    for (int t = 0; t < KSEL; ++t) {
        if (tid == 0) sel[t] = cur;
        float qx = sx[cur];
        float qy = sy[cur];
        float qz = sz[cur];

        float bv = -1.0f;
        int   bi = 0x7fffffff;
        // exact reference arithmetic: (dx*dx + dy*dy) + dz*dz, no fma; fminf;
        // strict > keeps smallest index on ties (j ascending = idx ascending)
#define UPD(J) { \
        float dx = __fsub_rn(x##J, qx); \
        float dy = __fsub_rn(y##J, qy); \
        float dz = __fsub_rn(z##J, qz); \
        float dd = __fadd_rn(__fadd_rn(__fmul_rn(dx, dx), __fmul_rn(dy, dy)), \
                             __fmul_rn(dz, dz)); \
        d##J = fminf(d##J, dd); \
        if (d##J > bv) { bv = d##J; bi = (J)*256 + tid; } }
        X16(UPD)
#undef UPD

        // pack: nonneg float bits are order-preserving as unsigned;
        // tie -> larger ~idx -> smaller idx (matches argmax first-occurrence)
        unsigned long long p =
            (((unsigned long long)__float_as_uint(bv)) << 32) |
            (unsigned int)(~bi);

        // DPP wave-64 max reduce into lane 63
        {
            unsigned int lo, hi, slo, shi;
#define DSTEP(CTRL) \
            lo = (unsigned int)p; hi = (unsigned int)(p >> 32); \
            slo = __builtin_amdgcn_update_dpp(0, (int)lo, CTRL, 0xf, 0xf, true); \
            shi = __builtin_amdgcn_update_dpp(0, (int)hi, CTRL, 0xf, 0xf, true); \
            p = dpp_max_step(p, slo, shi);
            DSTEP(0x111)  // row_shr:1
            DSTEP(0x112)  // row_shr:2
            DSTEP(0x114)  // row_shr:4
            DSTEP(0x118)  // row_shr:8
            DSTEP(0x142)  // row_bcast:15
            DSTEP(0x143)  // row_bcast:31
#undef DSTEP
        }

        int par = t & 1;
        if ((tid & 63) == 63) pwv[par][tid >> 6] = p;
        __syncthreads();

        unsigned long long c0 = pwv[par][0];
        unsigned long long c1 = pwv[par][1];
        unsigned long long c2 = pwv[par][2];
        unsigned long long c3 = pwv[par][3];
        unsigned long long m01 = (c0 > c1) ? c0 : c1;
        unsigned long long m23 = (c2 > c3) ? c2 : c3;
        unsigned long long mm  = (m01 > m23) ? m01 : m23;
        cur = (int)(~(unsigned int)(mm & 0xffffffffULL));
    }
    __syncthreads();

    // epilogue: write selections in parallel, coalesced
    for (int t = tid; t < KSEL; t += 256) {
        int c = sel[t];
        int g = b * NPTS + c;
        int m = b * KSEL + t;
        fp_int[m] = g;
        inv[g] = m;
        out_fp[m] = (float)g;
        out_subx[m * 3 + 0] = sx[c];
        out_subx[m * 3 + 1] = sy[c];
        out_subx[m * 3 + 2] = sz[c];
    }
}

// ---------------- bucketed scatter (post-fps) ------------------------------
// Replaces deg_kernel + scan_kernel + CSR scatter (R4): per-sampled-node
// fixed-capacity buckets. cnt[m] doubles as the in-degree of sampled node m
// (exact: every in-edge of a sampled dst lands here). Arrival order within a
// bucket is nondeterministic — same as the old CSR cursor scheme; aggregation
// tolerance already covers it. CAP=80 overflow is ~4e-13/node; clamp is for
// memory safety only.
__global__ void scatter_kernel(const int* __restrict__ src, const int* __restrict__ dst,
                               const int* __restrict__ inv,
                               int* __restrict__ cnt, int* __restrict__ col2)
{
    int e = blockIdx.x * blockDim.x + threadIdx.x;
    if (e < N_EDGES) {
        int ld = inv[dst[e]];
        if (ld >= 0) {
            int slot = atomicAdd(&cnt[ld], 1);
            if (slot < CAP) col2[ld * CAP + slot] = src[e];
        }
    }
}

// ---------------- fused agg (blocks 0..2047) + edge (blocks 2048..4095) ---
__global__ void agg_edge_kernel(const float* __restrict__ feat,
                                const int* __restrict__ cnt,
                                const int* __restrict__ col2,
                                float* __restrict__ out_subfeat,
                                const int* __restrict__ src,
                                const int* __restrict__ dst,
                                const int* __restrict__ inv,
                                const float* __restrict__ subx,
                                float* __restrict__ outd,
                                float* __restrict__ outw,
                                float* __restrict__ outm)
{
    if (blockIdx.x < 2048) {
        // mean aggregation: one wave per sampled node.
        // Dual-edge scheme: lanes 0-31 accumulate the even-edge stream (A),
        // lanes 32-63 the odd-edge stream (B); each lane loads a float4
        // (16 B — dwordx4 sweet spot). Per-column association is
        // bit-identical to the a/b two-stream unroll: Σ(even e) + Σ(odd e).
        int wid  = (blockIdx.x * blockDim.x + threadIdx.x) >> 6;
        int lane = threadIdx.x & 63;
        int half = lane >> 5;      // 0 = even-edge stream, 1 = odd-edge stream
        int l32  = lane & 31;      // column group: cols 4*l32 .. 4*l32+3
        int n = cnt[wid];          // exact in-degree of sampled node wid
        const int* cw = col2 + wid * CAP;
        float ax = 0.0f, ay = 0.0f, az = 0.0f, aw = 0.0f;
        int e = 0;
        for (; e + 1 < n; e += 2) {
            int sE = cw[e + half];
            float4 f = ((const float4*)(feat + (size_t)sE * D_FEAT))[l32];
            ax += f.x; ay += f.y; az += f.z; aw += f.w;
        }
        if (e < n && half == 0) {   // odd tail goes to the even stream (as before)
            int sE = cw[e];
            float4 f = ((const float4*)(feat + (size_t)sE * D_FEAT))[l32];
            ax += f.x; ay += f.y; az += f.z; aw += f.w;
        }
        // combine streams: lane l<32 holds A(cols 4l..), lane l+32 holds B(same cols)
        ax += __shfl_xor(ax, 32, 64);
        ay += __shfl_xor(ay, 32, 64);
        az += __shfl_xor(az, 32, 64);
        aw += __shfl_xor(aw, 32, 64);
        if (half == 0) {
            float dv = fmaxf((float)n, 1.0f);
            float4 o;
            o.x = ax / dv; o.y = ay / dv; o.z = az / dv; o.w = aw / dv;
            ((float4*)(out_subfeat + (size_t)wid * D_FEAT))[l32] = o;
        }
    } else {
        int e = (blockIdx.x - 2048) * blockDim.x + threadIdx.x;
        int ls = inv[src[e]];
        int ld = inv[dst[e]];
        bool mk = (ls >= 0) && (ld >= 0);
        float dx = 0.0f, dy = 0.0f, dz = 0.0f;
        if (mk) {
            dx = __fsub_rn(subx[ld * 3 + 0], subx[ls * 3 + 0]);
            dy = __fsub_rn(subx[ld * 3 + 1], subx[ls * 3 + 1]);
            dz = __fsub_rn(subx[ld * 3 + 2], subx[ls * 3 + 2]);
        }
        float w = sqrtf(__fadd_rn(__fadd_rn(__fmul_rn(dx, dx), __fmul_rn(dy, dy)),
                                  __fmul_rn(dz, dz)));
        outd[e * 3 + 0] = dx;
        outd[e * 3 + 1] = dy;
        outd[e * 3 + 2] = dz;
        outw[e] = w;
        outm[e] = mk ? 1.0f : 0.0f;
    }
}

// ---------------- launch ---------------------------------------------------
// Order: memset(cnt)=0, memset(inv)=0xFF (-1), fps, scatter, agg.
// scatter needs inv (fps); agg needs cnt/col2 (scatter).
extern "C" void kernel_launch(void* const* d_in, const int* in_sizes, int n_in,
                              void* d_out, int out_size, void* d_ws, size_t ws_size,
                              hipStream_t stream)
{
    const float* pos  = (const float*)d_in[0];   // [16384,3]
    const float* feat = (const float*)d_in[1];   // [16384,128]
    const int*   src  = (const int*)d_in[2];     // [524288]
    const int*   dst  = (const int*)d_in[3];     // [524288]

    float* out = (float*)d_out;
    float* out_subx    = out;                                 // [8192,3]
    float* out_subfeat = out_subx + (size_t)MSEL * 3;         // [8192,128]
    float* out_d       = out_subfeat + (size_t)MSEL * D_FEAT; // [524288,3]
    float* out_w       = out_d + (size_t)N_EDGES * 3;         // [524288]
    float* out_m       = out_w + (size_t)N_EDGES;             // [524288]
    float* out_fp      = out_m + (size_t)N_EDGES;             // [8192]

    int* fp_int = (int*)d_ws;            // 8192
    int* inv    = fp_int + MSEL;         // 16384
    int* cnt    = inv + N_NODES;         // 8192
    int* col2   = cnt + MSEL;            // 8192*80 = 655360
    // total ws usage: (8192+16384+8192+655360)*4 = 2.75 MB

    (void)hipMemsetAsync(cnt, 0, (size_t)MSEL * 4, stream);
    (void)hipMemsetAsync(inv, 0xFF, (size_t)N_NODES * 4, stream);  // inv = -1

    fps_kernel<<<BATCH, 256, 0, stream>>>(pos, fp_int, inv, out_subx, out_fp);

    scatter_kernel<<<N_EDGES / 256, 256, 0, stream>>>(src, dst, inv, cnt, col2);

    agg_edge_kernel<<<4096, 256, 0, stream>>>(feat, cnt, col2,
                                              out_subfeat, src, dst, inv, out_subx,
                                              out_d, out_w, out_m);
}